// Round 10
// baseline (250.549 us; speedup 1.0000x reference)
//
#include <hip/hip_runtime.h>

#define B_ 2
#define C_ 256
#define H_ 56
#define W_ 56
#define N_ 64
#define M_ 8
#define P_ 7
#define Y2_ (H_/2)               // 28 y-row pairs
#define Y4_ (H_/4)               // 14 y-row quads
#define SCTX_ 4                  // column chunks per ctx roi (box roi = whole)
#define JPN_ (1 + (M_)*SCTX_)    // 33 jobs per (b,n) -> 4224 blocks (fallback)
#define JP2_ (9*4)               // 36 px-pair jobs per (b,n) -> 4608 (path P)
#define WROW_ 8                  // padded weight-row stride (7 used + col7 = 0)

typedef _Float16 half2v __attribute__((ext_vector_type(2)));

#if __has_builtin(__builtin_amdgcn_fdot2)
#define FDOT2(a, b, c) __builtin_amdgcn_fdot2((a), (b), (c), false)
#else
static __device__ __forceinline__ float FDOT2(half2v a, half2v b, float c) {
    return fmaf((float)a.x, (float)b.x, fmaf((float)a.y, (float)b.y, c));
}
#endif

// ---- workspace layout (dword-element offsets) ----
#define F_FMT4 0
#define N_FMT4 (B_*Y4_*W_*C_*2)              // 802,816 dw  f16 y-QUAD-packed fmap
#define F_OUTS (F_FMT4 + N_FMT4)             // fallback: atomic staging
#define N_OUTS (B_*N_*49*C_)                 // 1,605,632 dw
#define WS_BYTES_F ((size_t)(F_OUTS + N_OUTS) * 4)       // 9.6 MB (proven)
// path P: plain-store partials.  part[bn][px][k 0..8][py][c]
#define F_PART (F_FMT4 + N_FMT4)
#define N_PART (B_*N_*7*9*7*C_)              // 14,450,688 dw = 57.8 MB
#define WS_BYTES_P ((size_t)(F_PART + N_PART) * 4)       // ~61.0 MB (ran in R9)

// prep kernel block ranges
#define PREP_T (B_*Y4_*4*2)                  // 224: transpose
#define PREP_N (PREP_T + 784)                // fallback: + zero outS

// ---------------------------------------------------------------------------
// k_prep (R2-verified).  Path P launches only the first PREP_T blocks.
__global__ __launch_bounds__(256) void k_prep(const float* __restrict__ fm,
                                              float* __restrict__ ws_f) {
    __shared__ float t[28 * 257 + 8];        // [x28][y4][c64], x-stride 257 pad
    int bid = blockIdx.x;
    int tid = (int)threadIdx.x;

    if (bid < PREP_T) {                      // ---- y4 pack-transpose ----
        int xh = bid & 1;
        int cg = (bid >> 1) & 3;
        int y4 = (bid >> 3) % Y4_;
        int b  = (bid >> 3) / Y4_;
        int c0 = cg * 64, x0 = xh * 28;
        for (int e = tid; e < 64 * 4 * 28; e += 256) {
            int c_l = e / 112, rem = e % 112;
            int y_l = rem / 28, x_l = rem % 28;
            t[x_l * 257 + y_l * 64 + c_l] =
                fm[(((size_t)b * C_ + c0 + c_l) * H_ + 4 * y4 + y_l) * W_ + x0 + x_l];
        }
        __syncthreads();
        uint2* dst = (uint2*)ws_f;
        for (int e = tid; e < 28 * 64; e += 256) {
            int x_l = e >> 6, c_l = e & 63;
            const float* p = &t[x_l * 257 + c_l];
            half2v lo, hi; uint2 o;
            lo.x = (_Float16)p[0];   lo.y = (_Float16)p[64];
            hi.x = (_Float16)p[128]; hi.y = (_Float16)p[192];
            o.x = __builtin_bit_cast(unsigned int, lo);
            o.y = __builtin_bit_cast(unsigned int, hi);
            dst[(((size_t)b * Y4_ + y4) * W_ + x0 + x_l) * (size_t)C_ + c0 + c_l] = o;
        }
        return;
    }

    {                                        // ---- zero outS (fallback only) ----
        int tz = (bid - PREP_T) * 256 + tid; // < 200,704
        float4 z = {0.0f, 0.0f, 0.0f, 0.0f};
        float4* dst = (float4*)(ws_f + F_OUTS);
        dst[tz * 2]     = z;
        dst[tz * 2 + 1] = z;
    }
}

// ---------------------------------------------------------------------------
// Shared weight-gen (R0-proven serial column-private form).
static __device__ __forceinline__ void gen_weights(int k, int b, int n, int tid,
                                                   const float* __restrict__ boxes,
                                                   const float* __restrict__ gt,
                                                   float (*s_wyf)[WROW_],
                                                   unsigned int* s_wy2,
                                                   float (*s_ax)[WROW_],
                                                   float& bx1, float& by1,
                                                   float& rw, float& rh) {
    const float* bp = boxes + ((size_t)b * N_ + n) * 4;
    float bx2, by2;
    if (k == 0) {
        bx1 = bp[0]; by1 = bp[1]; bx2 = bp[2]; by2 = bp[3];
    } else {
        const float* gp = gt + ((size_t)b * M_ + (k - 1)) * 4;
        bx1 = fminf(bp[0], gp[0]); by1 = fminf(bp[1], gp[1]);
        bx2 = fmaxf(bp[2], gp[2]); by2 = fmaxf(bp[3], gp[3]);
    }
    rw = fmaxf(bx2 - bx1, 1.0f);
    rh = fmaxf(by2 - by1, 1.0f);

    for (int e = tid; e < H_ * WROW_; e += 256) ((float*)s_wyf)[e] = 0.0f;
    for (int e = tid; e < W_ * WROW_; e += 256) ((float*)s_ax)[e] = 0.0f;
    __syncthreads();

    if (tid < P_) {                          // y samples, column-private
        int p = tid;
        float bin = rh / 7.0f;
        float gf  = ceilf(bin);
        int   g   = (int)gf;
        float ivg = 1.0f / gf;
        float start = by1 + (float)p * bin;
        for (int ss = 0; ss < g; ++ss) {
            float coord = start + ((float)ss + 0.5f) * bin * ivg;
            if (coord < -1.0f || coord > (float)H_) continue;
            float cc = fmaxf(coord, 0.0f);
            int low = (int)floorf(cc);
            int high; float l;
            if (low >= H_ - 1) { low = H_ - 1; high = H_ - 1; l = 0.0f; }
            else               { high = low + 1; l = cc - (float)low; }
            s_wyf[low][p]  += (1.0f - l) * ivg;
            s_wyf[high][p] += l * ivg;
        }
    } else if (tid >= 64 && tid < 64 + P_) { // x samples, column-private
        int p = tid - 64;
        float bin = rw / 7.0f;
        float gf  = ceilf(bin);
        int   g   = (int)gf;
        float ivg = 1.0f / gf;
        float fs  = (k == 0) ? ivg : ivg * (1.0f / (float)M_);
        float start = bx1 + (float)p * bin;
        for (int ss = 0; ss < g; ++ss) {
            float coord = start + ((float)ss + 0.5f) * bin * ivg;
            if (coord < -1.0f || coord > (float)W_) continue;
            float cc = fmaxf(coord, 0.0f);
            int low = (int)floorf(cc);
            int high; float l;
            if (low >= W_ - 1) { low = W_ - 1; high = W_ - 1; l = 0.0f; }
            else               { high = low + 1; l = cc - (float)low; }
            s_ax[low][p]  += (1.0f - l) * fs;
            s_ax[high][p] += l * fs;
        }
    }
    __syncthreads();

    if (tid < Y2_ * WROW_) {                 // pack y fp32 pairs -> half2
        int q2 = tid >> 3, col = tid & 7;
        half2v h;
        if (col < P_) { h.x = (_Float16)s_wyf[2 * q2][col]; h.y = (_Float16)s_wyf[2 * q2 + 1][col]; }
        else          { h.x = (_Float16)0.0f; h.y = (_Float16)0.0f; }
        s_wy2[tid] = __builtin_bit_cast(unsigned int, h);
    }
    __syncthreads();
}

// one (col i, py F) dot2 pair over the 4 rows of the quad
#define YQ3(F) \
    { cs[0][F] = FDOT2(w1[F], v0b, FDOT2(w0[F], v0a, cs[0][F]));   \
      cs[1][F] = FDOT2(w1[F], v1b, FDOT2(w0[F], v1a, cs[1][F]));   \
      cs[2][F] = FDOT2(w1[F], v2b, FDOT2(w0[F], v2a, cs[2][F]));   \
      cs[3][F] = FDOT2(w1[F], v3b, FDOT2(w0[F], v3a, cs[3][F])); }

// ---------------------------------------------------------------------------
// k_mainP (path P, R10): px-pair jobs, plain stores (R9-proven) + EXACT
// Y-SPARSITY.  R9 closed the ablation: loads ~5us, atomics ~2us, the common
// core (prologue + FDOT2 + x-stage) ~75us.  The core's waste is structural:
// all 7 py are computed over the whole y4 range, but a quad has nonzero
// weights in <=3 py for the dominant ctx rois (bin>=3) — ~55-60% of FDOT2s
// multiply exact zeros, and the +-1 padded quads are fully dead.  Fix: scan
// s_wyf per quad for first/last live py (exact), then per y4: skip dead
// quads (loads too); span<=3 -> block-uniform switch(f) with statically-
// indexed 3-py body (24 FDOT2); else full 7-py body.  Removed terms were
// exactly 0.0 (zero weight x finite in-bounds data) -> bit-identical output.
__global__ __launch_bounds__(256, 4) void k_mainP(const float* __restrict__ ws_f,
                                                  const float* __restrict__ boxes,
                                                  const float* __restrict__ gt,
                                                  float* __restrict__ part) {
    __shared__ float        s_wyf[H_][WROW_];
    __shared__ unsigned int s_wy2[Y2_ * WROW_];
    __shared__ float        s_ax[W_][WROW_];
    __shared__ int          s_pyf[Y4_];      // first live py per quad (7 = dead)
    __shared__ int          s_pyl[Y4_];      // last live py per quad

    int bid = blockIdx.x;
    int j   = bid % JP2_;                    // 0..35
    int n   = (bid / JP2_) & (N_ - 1);
    int b   = bid / (JP2_ * N_);
    int k   = j >> 2;                        // 0 = box, 1..8 = ctx union
    int s   = j & 3;
    int p0  = 2 * s;                         // px pair {p0, p0+1} (s==3: p0 only)
    int tid = (int)threadIdx.x;
    int c   = tid;

    float bx1, by1, rw, rh;
    gen_weights(k, b, n, tid, boxes, gt, s_wyf, s_wy2, s_ax, bx1, by1, rw, rh);

    // ---- exact per-quad live-py scan (s_wyf stable since pack barrier) ----
    if (tid < Y4_) {
        int f = 7, l = -1;
#pragma unroll
        for (int r = 0; r < 4; ++r)
#pragma unroll
            for (int p = 0; p < P_; ++p)
                if (s_wyf[4 * tid + r][p] != 0.0f) { f = min(f, p); l = max(l, p); }
        s_pyf[tid] = f;
        s_pyl[tid] = l;
    }
    __syncthreads();

    // ---- px-pair column support (R6-verified formulas) ----
    float binw = rw * (1.0f / 7.0f);
    float lo_f = bx1 + (float)p0 * binw;
    int   pe   = (p0 + 1 < P_) ? p0 + 2 : p0 + 1;
    float hi_f = bx1 + (float)pe * binw;
    int xs = min(max((int)floorf(fmaxf(lo_f, 0.0f)), 0), W_ - 1);
    int xe = min(max((int)floorf(fminf(hi_f, (float)W_)) + 1, 0), W_ - 1) + 1;

    int ylo = min(max((int)floorf(fmaxf(by1, 0.0f)), 0), H_ - 1);
    int yhi = min(max((int)floorf(by1 + rh) + 1, 0), H_ - 1) + 1;
    int ylo4 = ylo >> 2;
    int yhi4 = (yhi + 3) >> 2;

    const uint2* f4 = (const uint2*)ws_f + (size_t)b * (Y4_ * W_ * C_);

    float acc0[P_], acc1[P_];
#pragma unroll
    for (int q = 0; q < P_; ++q) { acc0[q] = 0.0f; acc1[q] = 0.0f; }

    if (xs < xe) {                           // empty support -> store zeros
        for (int x = xs; x < xe; x += 4) {
            float cs[4][P_];
#pragma unroll
            for (int i = 0; i < 4; ++i)
#pragma unroll
                for (int py = 0; py < P_; ++py) cs[i][py] = 0.0f;

            // x+1..x+3 over-reads stay inside d_ws; garbage never enters acc.
            const uint2* cp = f4 + ((size_t)(ylo4 * W_ + x)) * C_ + c;
            for (int y4 = ylo4; y4 < yhi4; ++y4) {
                int f = s_pyf[y4];
                if (f > 6) { cp += W_ * C_; continue; }      // dead quad: skip
                int l = s_pyl[y4];

                uint2 d0 = cp[0];
                uint2 d1 = cp[C_];
                uint2 d2 = cp[2 * C_];
                uint2 d3 = cp[3 * C_];
                uint4 wa0 = *(const uint4*)&s_wy2[(2 * y4) * WROW_];
                uint4 wb0 = *(const uint4*)&s_wy2[(2 * y4) * WROW_ + 4];
                uint4 wa1 = *(const uint4*)&s_wy2[(2 * y4 + 1) * WROW_];
                uint4 wb1 = *(const uint4*)&s_wy2[(2 * y4 + 1) * WROW_ + 4];
                half2v w0[7], w1[7];
                w0[0] = __builtin_bit_cast(half2v, wa0.x);
                w0[1] = __builtin_bit_cast(half2v, wa0.y);
                w0[2] = __builtin_bit_cast(half2v, wa0.z);
                w0[3] = __builtin_bit_cast(half2v, wa0.w);
                w0[4] = __builtin_bit_cast(half2v, wb0.x);
                w0[5] = __builtin_bit_cast(half2v, wb0.y);
                w0[6] = __builtin_bit_cast(half2v, wb0.z);
                w1[0] = __builtin_bit_cast(half2v, wa1.x);
                w1[1] = __builtin_bit_cast(half2v, wa1.y);
                w1[2] = __builtin_bit_cast(half2v, wa1.z);
                w1[3] = __builtin_bit_cast(half2v, wa1.w);
                w1[4] = __builtin_bit_cast(half2v, wb1.x);
                w1[5] = __builtin_bit_cast(half2v, wb1.y);
                w1[6] = __builtin_bit_cast(half2v, wb1.z);
                half2v v0a = __builtin_bit_cast(half2v, d0.x);
                half2v v0b = __builtin_bit_cast(half2v, d0.y);
                half2v v1a = __builtin_bit_cast(half2v, d1.x);
                half2v v1b = __builtin_bit_cast(half2v, d1.y);
                half2v v2a = __builtin_bit_cast(half2v, d2.x);
                half2v v2b = __builtin_bit_cast(half2v, d2.y);
                half2v v3a = __builtin_bit_cast(half2v, d3.x);
                half2v v3b = __builtin_bit_cast(half2v, d3.y);

                int fs = (l - f <= 2) ? f : 7;   // 7 = full fallback
                switch (fs) {                    // block-uniform branch
                    case 0: YQ3(0) YQ3(1) YQ3(2) break;
                    case 1: YQ3(1) YQ3(2) YQ3(3) break;
                    case 2: YQ3(2) YQ3(3) YQ3(4) break;
                    case 3: YQ3(3) YQ3(4) YQ3(5) break;
                    case 4: YQ3(4) YQ3(5) YQ3(6) break;
                    case 5: YQ3(5) YQ3(6) break;
                    case 6: YQ3(6) break;
                    default:
                        YQ3(0) YQ3(1) YQ3(2) YQ3(3) YQ3(4) YQ3(5) YQ3(6)
                        break;
                }
                cp += W_ * C_;
            }

            // ---- x-stage: only the owned px pair ----
#pragma unroll
            for (int i = 0; i < 4; ++i) {
                if (x + i < xe) {                     // wave-uniform
                    float2 axv = *(const float2*)&s_ax[x + i][p0];
#pragma unroll
                    for (int py = 0; py < P_; ++py) {
                        acc0[py] = fmaf(axv.x, cs[i][py], acc0[py]);
                        acc1[py] = fmaf(axv.y, cs[i][py], acc1[py]);
                    }
                }
            }
        }
    }

    // ---- epilogue: PLAIN coalesced stores to private slots ----
    size_t bn = (size_t)b * N_ + n;
    float* pp = part + (((bn * 7 + p0) * 9 + k) * 7) * 256 + c;
#pragma unroll
    for (int py = 0; py < P_; ++py) pp[py * 256] = acc0[py];
    if (p0 + 1 < P_) {
        float* pq = part + (((bn * 7 + p0 + 1) * 9 + k) * 7) * 256 + c;
#pragma unroll
        for (int py = 0; py < P_; ++py) pq[py * 256] = acc1[py];
    }
}

// ---------------------------------------------------------------------------
// k_reduce (path P, R9-proven): out[bn][c][py*7+px] = sum_k part[...].
__global__ __launch_bounds__(256) void k_reduce(const float* __restrict__ part,
                                                float* __restrict__ out) {
    __shared__ float t[49 * 65];
    int bid = blockIdx.x;                    // bn*4 + cg
    int cg  = bid & 3;
    int bn  = bid >> 2;
    int tid = (int)threadIdx.x;
    const float* pb = part + (size_t)bn * (7 * 9 * 7 * 256) + cg * 64;
    for (int e = tid; e < 49 * 64; e += 256) {
        int q = e >> 6, cl = e & 63;
        int py = q / 7, px = q - py * 7;
        const float* p0 = pb + ((size_t)(px * 63 + py)) * 256 + cl;
        float sum = 0.0f;
#pragma unroll
        for (int k = 0; k < 9; ++k) sum += p0[(size_t)k * (7 * 256)];
        t[q * 65 + cl] = sum;
    }
    __syncthreads();
    float* dst = out + (size_t)bn * (C_ * 49) + (size_t)cg * 64 * 49;
    for (int e = tid; e < 64 * 49; e += 256) {
        int cl = e / 49, q = e - cl * 49;
        dst[e] = t[q * 65 + cl];
    }
}

// ---------------------------------------------------------------------------
// FALLBACK PATH (ws too small): R4-verbatim k_main + k_final (proven 149.4).
__global__ __launch_bounds__(256, 4) void k_main(const float* __restrict__ ws_f,
                                                 const float* __restrict__ boxes,
                                                 const float* __restrict__ gt,
                                                 float* __restrict__ outs) {
    __shared__ float        s_wyf[H_][WROW_];
    __shared__ unsigned int s_wy2[Y2_ * WROW_];
    __shared__ float        s_ax[W_][WROW_];

    int bid = blockIdx.x;
    int j   = bid % JPN_;
    int n   = (bid / JPN_) & (N_ - 1);
    int b   = bid / (JPN_ * N_);
    int k, s;
    if (j == 0) { k = 0; s = 0; }
    else        { k = 1 + ((j - 1) >> 2); s = (j - 1) & 3; }
    int tid = (int)threadIdx.x;
    int c   = tid;

    float bx1, by1, rw, rh;
    gen_weights(k, b, n, tid, boxes, gt, s_wyf, s_wy2, s_ax, bx1, by1, rw, rh);

    int xlo = min(max((int)floorf(fmaxf(bx1, 0.0f)), 0), W_ - 1);
    int xhi = min(max((int)floorf(bx1 + rw) + 1, 0), W_ - 1) + 1;
    int ylo = min(max((int)floorf(fmaxf(by1, 0.0f)), 0), H_ - 1);
    int yhi = min(max((int)floorf(by1 + rh) + 1, 0), H_ - 1) + 1;
    int xs, xe;
    if (k == 0) { xs = xlo; xe = xhi; }
    else {
        int cw = (xhi - xlo + SCTX_ - 1) >> 2;
        xs = xlo + s * cw;
        xe = min(xs + cw, xhi);
    }
    if (xs >= xe) return;

    int ylo4 = ylo >> 2;
    int yhi4 = (yhi + 3) >> 2;

    const uint2* f4 = (const uint2*)ws_f + (size_t)b * (Y4_ * W_ * C_);

    float acc[49];
#pragma unroll
    for (int q = 0; q < 49; ++q) acc[q] = 0.0f;
    int live = 0;

    for (int x = xs; x < xe; x += 4) {
        float cs[4][P_];
#pragma unroll
        for (int i = 0; i < 4; ++i)
#pragma unroll
            for (int py = 0; py < P_; ++py) cs[i][py] = 0.0f;

        const uint2* cp = f4 + ((size_t)(ylo4 * W_ + x)) * C_ + c;

        uint2 d0 = cp[0];
        uint2 d1 = cp[C_];
        uint2 d2 = cp[2 * C_];
        uint2 d3 = cp[3 * C_];
        for (int y4 = ylo4; y4 < yhi4; ++y4) {
            size_t nstep = (y4 + 1 < yhi4) ? (size_t)(W_ * C_) : 0;
            const uint2* cq = cp + nstep;
            uint2 e0 = cq[0];
            uint2 e1 = cq[C_];
            uint2 e2 = cq[2 * C_];
            uint2 e3 = cq[3 * C_];

            uint4 wa0 = *(const uint4*)&s_wy2[(2 * y4) * WROW_];
            uint4 wb0 = *(const uint4*)&s_wy2[(2 * y4) * WROW_ + 4];
            uint4 wa1 = *(const uint4*)&s_wy2[(2 * y4 + 1) * WROW_];
            uint4 wb1 = *(const uint4*)&s_wy2[(2 * y4 + 1) * WROW_ + 4];
            half2v w0[7], w1[7];
            w0[0] = __builtin_bit_cast(half2v, wa0.x);
            w0[1] = __builtin_bit_cast(half2v, wa0.y);
            w0[2] = __builtin_bit_cast(half2v, wa0.z);
            w0[3] = __builtin_bit_cast(half2v, wa0.w);
            w0[4] = __builtin_bit_cast(half2v, wb0.x);
            w0[5] = __builtin_bit_cast(half2v, wb0.y);
            w0[6] = __builtin_bit_cast(half2v, wb0.z);
            w1[0] = __builtin_bit_cast(half2v, wa1.x);
            w1[1] = __builtin_bit_cast(half2v, wa1.y);
            w1[2] = __builtin_bit_cast(half2v, wa1.z);
            w1[3] = __builtin_bit_cast(half2v, wa1.w);
            w1[4] = __builtin_bit_cast(half2v, wb1.x);
            w1[5] = __builtin_bit_cast(half2v, wb1.y);
            w1[6] = __builtin_bit_cast(half2v, wb1.z);
            half2v v0a = __builtin_bit_cast(half2v, d0.x);
            half2v v0b = __builtin_bit_cast(half2v, d0.y);
            half2v v1a = __builtin_bit_cast(half2v, d1.x);
            half2v v1b = __builtin_bit_cast(half2v, d1.y);
            half2v v2a = __builtin_bit_cast(half2v, d2.x);
            half2v v2b = __builtin_bit_cast(half2v, d2.y);
            half2v v3a = __builtin_bit_cast(half2v, d3.x);
            half2v v3b = __builtin_bit_cast(half2v, d3.y);
#pragma unroll
            for (int py = 0; py < P_; ++py) {
                cs[0][py] = FDOT2(w1[py], v0b, FDOT2(w0[py], v0a, cs[0][py]));
                cs[1][py] = FDOT2(w1[py], v1b, FDOT2(w0[py], v1a, cs[1][py]));
                cs[2][py] = FDOT2(w1[py], v2b, FDOT2(w0[py], v2a, cs[2][py]));
                cs[3][py] = FDOT2(w1[py], v3b, FDOT2(w0[py], v3a, cs[3][py]));
            }
            d0 = e0; d1 = e1; d2 = e2; d3 = e3;
            cp = cq;
        }

#pragma unroll
        for (int i = 0; i < 4; ++i) {
            if (x + i < xe) {
                float av[8];
                *(float4*)(&av[0]) = *(const float4*)&s_ax[x + i][0];
                *(float4*)(&av[4]) = *(const float4*)&s_ax[x + i][4];
#pragma unroll
                for (int px = 0; px < P_; ++px) {
                    float w = av[px];
                    if (w != 0.0f) {
                        live |= 1 << px;
#pragma unroll
                        for (int py = 0; py < P_; ++py)
                            acc[py * P_ + px] = fmaf(w, cs[i][py], acc[py * P_ + px]);
                    }
                }
            }
        }
    }

    float* os = outs + ((size_t)b * N_ + n) * (49 * C_) + c;
#pragma unroll
    for (int px = 0; px < P_; ++px) {
        if (live & (1 << px)) {
#pragma unroll
            for (int py = 0; py < P_; ++py)
                atomicAdd(os + (py * P_ + px) * C_, acc[py * P_ + px]);
        }
    }
}

__global__ __launch_bounds__(256) void k_final(const float* __restrict__ outs,
                                               float* __restrict__ out) {
    __shared__ float t[49 * 65];
    int bid = blockIdx.x;
    int cg  = bid & 3;
    int bn  = bid >> 2;
    int tid = (int)threadIdx.x;
    const float* src = outs + (size_t)bn * (49 * C_) + cg * 64;
    for (int e = tid; e < 49 * 64; e += 256) {
        int q = e >> 6, c = e & 63;
        t[q * 65 + c] = src[q * C_ + c];
    }
    __syncthreads();
    float* dst = out + (size_t)bn * (C_ * 49) + (size_t)cg * 64 * 49;
    for (int e = tid; e < 64 * 49; e += 256) {
        int c = e / 49, q = e - c * 49;
        dst[e] = t[q * 65 + c];
    }
}

// ---------------------------------------------------------------------------
extern "C" void kernel_launch(void* const* d_in, const int* in_sizes, int n_in,
                              void* d_out, int out_size, void* d_ws, size_t ws_size,
                              hipStream_t stream) {
    const float* fm    = (const float*)d_in[0];
    const float* boxes = (const float*)d_in[1];
    const float* gt    = (const float*)d_in[2];
    float* ws_f = (float*)d_ws;
    float* out  = (float*)d_out;

    if (ws_size >= WS_BYTES_P) {
        // ---- path P: atomic-free + exact y-sparsity ----
        float* part = ws_f + F_PART;
        k_prep<<<PREP_T, 256, 0, stream>>>(fm, ws_f);
        k_mainP<<<B_ * N_ * JP2_, 256, 0, stream>>>(ws_f, boxes, gt, part);
        k_reduce<<<B_ * N_ * 4, 256, 0, stream>>>(part, out);
    } else {
        // ---- fallback: R4-verbatim proven pipeline ----
        float* outs = ws_f + F_OUTS;
        k_prep<<<PREP_N, 256, 0, stream>>>(fm, ws_f);
        k_main<<<B_ * N_ * JPN_, 256, 0, stream>>>(ws_f, boxes, gt, outs);
        k_final<<<B_ * N_ * 4, 256, 0, stream>>>(outs, out);
    }
}

// Round 11
// 135.401 us; speedup vs baseline: 1.8504x; 1.8504x over previous
//
#include <hip/hip_runtime.h>

#define B_ 2
#define C_ 256
#define H_ 56
#define W_ 56
#define N_ 64
#define M_ 8
#define P_ 7
#define Y2_ (H_/2)               // 28 y-row pairs
#define Y4_ (H_/4)               // 14 y-row quads
#define SCTX_ 4                  // column chunks per ctx roi (box roi = whole)
#define JPN_ (1 + (M_)*SCTX_)    // 33 jobs per (b,n) -> 4224 blocks (fallback)
#define JP2_ (9*4)               // 36 px-pair jobs per (b,n) -> 4608 (path P)
#define WROW_ 8                  // padded weight-row stride (7 used + col7 = 0)

typedef _Float16 half2v __attribute__((ext_vector_type(2)));

#if __has_builtin(__builtin_amdgcn_fdot2)
#define FDOT2(a, b, c) __builtin_amdgcn_fdot2((a), (b), (c), false)
#else
static __device__ __forceinline__ float FDOT2(half2v a, half2v b, float c) {
    return fmaf((float)a.x, (float)b.x, fmaf((float)a.y, (float)b.y, c));
}
#endif

// ---- workspace layout (dword-element offsets) ----
#define F_FMT4 0
#define N_FMT4 (B_*Y4_*W_*C_*2)              // 802,816 dw  f16 y-QUAD-packed fmap
#define F_OUTS (F_FMT4 + N_FMT4)             // fallback: atomic staging
#define N_OUTS (B_*N_*49*C_)                 // 1,605,632 dw
#define WS_BYTES_F ((size_t)(F_OUTS + N_OUTS) * 4)       // 9.6 MB (proven)
// path P: plain-store partials.  part[bn][px][k 0..8][py][c]
#define F_PART (F_FMT4 + N_FMT4)
#define N_PART (B_*N_*7*9*7*C_)              // 14,450,688 dw = 57.8 MB
#define WS_BYTES_P ((size_t)(F_PART + N_PART) * 4)       // ~61.0 MB (ran R9/R10)

// prep kernel block ranges
#define PREP_T (B_*Y4_*4*2)                  // 224: transpose
#define PREP_N (PREP_T + 784)                // fallback: + zero outS

// ---------------------------------------------------------------------------
// k_prep (R2-verified).  Path P launches only the first PREP_T blocks.
__global__ __launch_bounds__(256) void k_prep(const float* __restrict__ fm,
                                              float* __restrict__ ws_f) {
    __shared__ float t[28 * 257 + 8];        // [x28][y4][c64], x-stride 257 pad
    int bid = blockIdx.x;
    int tid = (int)threadIdx.x;

    if (bid < PREP_T) {                      // ---- y4 pack-transpose ----
        int xh = bid & 1;
        int cg = (bid >> 1) & 3;
        int y4 = (bid >> 3) % Y4_;
        int b  = (bid >> 3) / Y4_;
        int c0 = cg * 64, x0 = xh * 28;
        for (int e = tid; e < 64 * 4 * 28; e += 256) {
            int c_l = e / 112, rem = e % 112;
            int y_l = rem / 28, x_l = rem % 28;
            t[x_l * 257 + y_l * 64 + c_l] =
                fm[(((size_t)b * C_ + c0 + c_l) * H_ + 4 * y4 + y_l) * W_ + x0 + x_l];
        }
        __syncthreads();
        uint2* dst = (uint2*)ws_f;
        for (int e = tid; e < 28 * 64; e += 256) {
            int x_l = e >> 6, c_l = e & 63;
            const float* p = &t[x_l * 257 + c_l];
            half2v lo, hi; uint2 o;
            lo.x = (_Float16)p[0];   lo.y = (_Float16)p[64];
            hi.x = (_Float16)p[128]; hi.y = (_Float16)p[192];
            o.x = __builtin_bit_cast(unsigned int, lo);
            o.y = __builtin_bit_cast(unsigned int, hi);
            dst[(((size_t)b * Y4_ + y4) * W_ + x0 + x_l) * (size_t)C_ + c0 + c_l] = o;
        }
        return;
    }

    {                                        // ---- zero outS (fallback only) ----
        int tz = (bid - PREP_T) * 256 + tid; // < 200,704
        float4 z = {0.0f, 0.0f, 0.0f, 0.0f};
        float4* dst = (float4*)(ws_f + F_OUTS);
        dst[tz * 2]     = z;
        dst[tz * 2 + 1] = z;
    }
}

// ---------------------------------------------------------------------------
// Shared weight-gen (R0-proven serial column-private form).
static __device__ __forceinline__ void gen_weights(int k, int b, int n, int tid,
                                                   const float* __restrict__ boxes,
                                                   const float* __restrict__ gt,
                                                   float (*s_wyf)[WROW_],
                                                   unsigned int* s_wy2,
                                                   float (*s_ax)[WROW_],
                                                   float& bx1, float& by1,
                                                   float& rw, float& rh) {
    const float* bp = boxes + ((size_t)b * N_ + n) * 4;
    float bx2, by2;
    if (k == 0) {
        bx1 = bp[0]; by1 = bp[1]; bx2 = bp[2]; by2 = bp[3];
    } else {
        const float* gp = gt + ((size_t)b * M_ + (k - 1)) * 4;
        bx1 = fminf(bp[0], gp[0]); by1 = fminf(bp[1], gp[1]);
        bx2 = fmaxf(bp[2], gp[2]); by2 = fmaxf(bp[3], gp[3]);
    }
    rw = fmaxf(bx2 - bx1, 1.0f);
    rh = fmaxf(by2 - by1, 1.0f);

    for (int e = tid; e < H_ * WROW_; e += 256) ((float*)s_wyf)[e] = 0.0f;
    for (int e = tid; e < W_ * WROW_; e += 256) ((float*)s_ax)[e] = 0.0f;
    __syncthreads();

    if (tid < P_) {                          // y samples, column-private
        int p = tid;
        float bin = rh / 7.0f;
        float gf  = ceilf(bin);
        int   g   = (int)gf;
        float ivg = 1.0f / gf;
        float start = by1 + (float)p * bin;
        for (int ss = 0; ss < g; ++ss) {
            float coord = start + ((float)ss + 0.5f) * bin * ivg;
            if (coord < -1.0f || coord > (float)H_) continue;
            float cc = fmaxf(coord, 0.0f);
            int low = (int)floorf(cc);
            int high; float l;
            if (low >= H_ - 1) { low = H_ - 1; high = H_ - 1; l = 0.0f; }
            else               { high = low + 1; l = cc - (float)low; }
            s_wyf[low][p]  += (1.0f - l) * ivg;
            s_wyf[high][p] += l * ivg;
        }
    } else if (tid >= 64 && tid < 64 + P_) { // x samples, column-private
        int p = tid - 64;
        float bin = rw / 7.0f;
        float gf  = ceilf(bin);
        int   g   = (int)gf;
        float ivg = 1.0f / gf;
        float fs  = (k == 0) ? ivg : ivg * (1.0f / (float)M_);
        float start = bx1 + (float)p * bin;
        for (int ss = 0; ss < g; ++ss) {
            float coord = start + ((float)ss + 0.5f) * bin * ivg;
            if (coord < -1.0f || coord > (float)W_) continue;
            float cc = fmaxf(coord, 0.0f);
            int low = (int)floorf(cc);
            int high; float l;
            if (low >= W_ - 1) { low = W_ - 1; high = W_ - 1; l = 0.0f; }
            else               { high = low + 1; l = cc - (float)low; }
            s_ax[low][p]  += (1.0f - l) * fs;
            s_ax[high][p] += l * fs;
        }
    }
    __syncthreads();

    if (tid < Y2_ * WROW_) {                 // pack y fp32 pairs -> half2
        int q2 = tid >> 3, col = tid & 7;
        half2v h;
        if (col < P_) { h.x = (_Float16)s_wyf[2 * q2][col]; h.y = (_Float16)s_wyf[2 * q2 + 1][col]; }
        else          { h.x = (_Float16)0.0f; h.y = (_Float16)0.0f; }
        s_wy2[tid] = __builtin_bit_cast(unsigned int, h);
    }
    __syncthreads();
}

// one (py F) dot2 pair across the quad's 4 columns — ALL indices static
#define YQ3(F) \
    { cs[0][F] = FDOT2(w1[F], v0b, FDOT2(w0[F], v0a, cs[0][F]));   \
      cs[1][F] = FDOT2(w1[F], v1b, FDOT2(w0[F], v1a, cs[1][F]));   \
      cs[2][F] = FDOT2(w1[F], v2b, FDOT2(w0[F], v2a, cs[2][F]));   \
      cs[3][F] = FDOT2(w1[F], v3b, FDOT2(w0[F], v3a, cs[3][F])); }

// ---------------------------------------------------------------------------
// k_mainP (path P, R11): R9's proven body + EXACT y-sparsity, spill-proof.
// R10's switch(f) encoding spilled (WRITE 56->298MB, FETCH 9.7->76MB:
// scratch traffic; rule-#20 class failure) and was 2.4x slower — the theory
// (>=50% of FDOT2s multiply exact zeros) was never tested.  R11 re-encodes:
// per-quad live-py BITMASK (exact, scanned from s_wyf) + 7 independently
// guarded static YQ3 blocks.  cs[][] indices all compile-time; guards are
// uniform scalar branches; dead quads (mask==0: the pad/out-of-support
// quads) skip their loads too.  Removed terms were exactly 0.0 x finite ->
// bit-identical output.  Everything else R9-verbatim.
__global__ __launch_bounds__(256, 4) void k_mainP(const float* __restrict__ ws_f,
                                                  const float* __restrict__ boxes,
                                                  const float* __restrict__ gt,
                                                  float* __restrict__ part) {
    __shared__ float        s_wyf[H_][WROW_];
    __shared__ unsigned int s_wy2[Y2_ * WROW_];
    __shared__ float        s_ax[W_][WROW_];
    __shared__ int          s_lm[Y4_];       // live-py bitmask per quad

    int bid = blockIdx.x;
    int j   = bid % JP2_;                    // 0..35
    int n   = (bid / JP2_) & (N_ - 1);
    int b   = bid / (JP2_ * N_);
    int k   = j >> 2;                        // 0 = box, 1..8 = ctx union
    int s   = j & 3;
    int p0  = 2 * s;                         // px pair {p0, p0+1} (s==3: p0 only)
    int tid = (int)threadIdx.x;
    int c   = tid;

    float bx1, by1, rw, rh;
    gen_weights(k, b, n, tid, boxes, gt, s_wyf, s_wy2, s_ax, bx1, by1, rw, rh);

    // ---- exact per-quad live-py bitmask (s_wyf stable after pack barrier) ----
    if (tid < Y4_) {
        int m = 0;
#pragma unroll
        for (int r = 0; r < 4; ++r)
#pragma unroll
            for (int p = 0; p < P_; ++p)
                if (s_wyf[4 * tid + r][p] != 0.0f) m |= 1 << p;
        s_lm[tid] = m;
    }
    __syncthreads();

    // ---- px-pair column support (R6-verified formulas) ----
    float binw = rw * (1.0f / 7.0f);
    float lo_f = bx1 + (float)p0 * binw;
    int   pe   = (p0 + 1 < P_) ? p0 + 2 : p0 + 1;
    float hi_f = bx1 + (float)pe * binw;
    int xs = min(max((int)floorf(fmaxf(lo_f, 0.0f)), 0), W_ - 1);
    int xe = min(max((int)floorf(fminf(hi_f, (float)W_)) + 1, 0), W_ - 1) + 1;

    int ylo = min(max((int)floorf(fmaxf(by1, 0.0f)), 0), H_ - 1);
    int yhi = min(max((int)floorf(by1 + rh) + 1, 0), H_ - 1) + 1;
    int ylo4 = ylo >> 2;
    int yhi4 = (yhi + 3) >> 2;

    const uint2* f4 = (const uint2*)ws_f + (size_t)b * (Y4_ * W_ * C_);

    float acc0[P_], acc1[P_];
#pragma unroll
    for (int q = 0; q < P_; ++q) { acc0[q] = 0.0f; acc1[q] = 0.0f; }

    if (xs < xe) {                           // empty support -> store zeros
        for (int x = xs; x < xe; x += 4) {
            float cs[4][P_];
#pragma unroll
            for (int i = 0; i < 4; ++i)
#pragma unroll
                for (int py = 0; py < P_; ++py) cs[i][py] = 0.0f;

            // x+1..x+3 over-reads stay inside d_ws; garbage never enters acc.
            const uint2* cp = f4 + ((size_t)(ylo4 * W_ + x)) * C_ + c;
            for (int y4 = ylo4; y4 < yhi4; ++y4) {
                int lm = s_lm[y4];
                if (lm == 0) { cp += W_ * C_; continue; }    // dead quad: skip
                uint2 d0 = cp[0];
                uint2 d1 = cp[C_];
                uint2 d2 = cp[2 * C_];
                uint2 d3 = cp[3 * C_];
                uint4 wa0 = *(const uint4*)&s_wy2[(2 * y4) * WROW_];
                uint4 wb0 = *(const uint4*)&s_wy2[(2 * y4) * WROW_ + 4];
                uint4 wa1 = *(const uint4*)&s_wy2[(2 * y4 + 1) * WROW_];
                uint4 wb1 = *(const uint4*)&s_wy2[(2 * y4 + 1) * WROW_ + 4];
                half2v w0[7], w1[7];
                w0[0] = __builtin_bit_cast(half2v, wa0.x);
                w0[1] = __builtin_bit_cast(half2v, wa0.y);
                w0[2] = __builtin_bit_cast(half2v, wa0.z);
                w0[3] = __builtin_bit_cast(half2v, wa0.w);
                w0[4] = __builtin_bit_cast(half2v, wb0.x);
                w0[5] = __builtin_bit_cast(half2v, wb0.y);
                w0[6] = __builtin_bit_cast(half2v, wb0.z);
                w1[0] = __builtin_bit_cast(half2v, wa1.x);
                w1[1] = __builtin_bit_cast(half2v, wa1.y);
                w1[2] = __builtin_bit_cast(half2v, wa1.z);
                w1[3] = __builtin_bit_cast(half2v, wa1.w);
                w1[4] = __builtin_bit_cast(half2v, wb1.x);
                w1[5] = __builtin_bit_cast(half2v, wb1.y);
                w1[6] = __builtin_bit_cast(half2v, wb1.z);
                half2v v0a = __builtin_bit_cast(half2v, d0.x);
                half2v v0b = __builtin_bit_cast(half2v, d0.y);
                half2v v1a = __builtin_bit_cast(half2v, d1.x);
                half2v v1b = __builtin_bit_cast(half2v, d1.y);
                half2v v2a = __builtin_bit_cast(half2v, d2.x);
                half2v v2b = __builtin_bit_cast(half2v, d2.y);
                half2v v3a = __builtin_bit_cast(half2v, d3.x);
                half2v v3b = __builtin_bit_cast(half2v, d3.y);

                if (lm & 0x01) YQ3(0)
                if (lm & 0x02) YQ3(1)
                if (lm & 0x04) YQ3(2)
                if (lm & 0x08) YQ3(3)
                if (lm & 0x10) YQ3(4)
                if (lm & 0x20) YQ3(5)
                if (lm & 0x40) YQ3(6)
                cp += W_ * C_;
            }

            // ---- x-stage: only the owned px pair ----
#pragma unroll
            for (int i = 0; i < 4; ++i) {
                if (x + i < xe) {                     // wave-uniform
                    float2 axv = *(const float2*)&s_ax[x + i][p0];
#pragma unroll
                    for (int py = 0; py < P_; ++py) {
                        acc0[py] = fmaf(axv.x, cs[i][py], acc0[py]);
                        acc1[py] = fmaf(axv.y, cs[i][py], acc1[py]);
                    }
                }
            }
        }
    }

    // ---- epilogue: PLAIN coalesced stores to private slots ----
    size_t bn = (size_t)b * N_ + n;
    float* pp = part + (((bn * 7 + p0) * 9 + k) * 7) * 256 + c;
#pragma unroll
    for (int py = 0; py < P_; ++py) pp[py * 256] = acc0[py];
    if (p0 + 1 < P_) {
        float* pq = part + (((bn * 7 + p0 + 1) * 9 + k) * 7) * 256 + c;
#pragma unroll
        for (int py = 0; py < P_; ++py) pq[py * 256] = acc1[py];
    }
}

// ---------------------------------------------------------------------------
// k_reduce (path P, R9-proven): out[bn][c][py*7+px] = sum_k part[...].
__global__ __launch_bounds__(256) void k_reduce(const float* __restrict__ part,
                                                float* __restrict__ out) {
    __shared__ float t[49 * 65];
    int bid = blockIdx.x;                    // bn*4 + cg
    int cg  = bid & 3;
    int bn  = bid >> 2;
    int tid = (int)threadIdx.x;
    const float* pb = part + (size_t)bn * (7 * 9 * 7 * 256) + cg * 64;
    for (int e = tid; e < 49 * 64; e += 256) {
        int q = e >> 6, cl = e & 63;
        int py = q / 7, px = q - py * 7;
        const float* p0 = pb + ((size_t)(px * 63 + py)) * 256 + cl;
        float sum = 0.0f;
#pragma unroll
        for (int k = 0; k < 9; ++k) sum += p0[(size_t)k * (7 * 256)];
        t[q * 65 + cl] = sum;
    }
    __syncthreads();
    float* dst = out + (size_t)bn * (C_ * 49) + (size_t)cg * 64 * 49;
    for (int e = tid; e < 64 * 49; e += 256) {
        int cl = e / 49, q = e - cl * 49;
        dst[e] = t[q * 65 + cl];
    }
}

// ---------------------------------------------------------------------------
// FALLBACK PATH (ws too small): R4-verbatim k_main + k_final (proven 149.4).
__global__ __launch_bounds__(256, 4) void k_main(const float* __restrict__ ws_f,
                                                 const float* __restrict__ boxes,
                                                 const float* __restrict__ gt,
                                                 float* __restrict__ outs) {
    __shared__ float        s_wyf[H_][WROW_];
    __shared__ unsigned int s_wy2[Y2_ * WROW_];
    __shared__ float        s_ax[W_][WROW_];

    int bid = blockIdx.x;
    int j   = bid % JPN_;
    int n   = (bid / JPN_) & (N_ - 1);
    int b   = bid / (JPN_ * N_);
    int k, s;
    if (j == 0) { k = 0; s = 0; }
    else        { k = 1 + ((j - 1) >> 2); s = (j - 1) & 3; }
    int tid = (int)threadIdx.x;
    int c   = tid;

    float bx1, by1, rw, rh;
    gen_weights(k, b, n, tid, boxes, gt, s_wyf, s_wy2, s_ax, bx1, by1, rw, rh);

    int xlo = min(max((int)floorf(fmaxf(bx1, 0.0f)), 0), W_ - 1);
    int xhi = min(max((int)floorf(bx1 + rw) + 1, 0), W_ - 1) + 1;
    int ylo = min(max((int)floorf(fmaxf(by1, 0.0f)), 0), H_ - 1);
    int yhi = min(max((int)floorf(by1 + rh) + 1, 0), H_ - 1) + 1;
    int xs, xe;
    if (k == 0) { xs = xlo; xe = xhi; }
    else {
        int cw = (xhi - xlo + SCTX_ - 1) >> 2;
        xs = xlo + s * cw;
        xe = min(xs + cw, xhi);
    }
    if (xs >= xe) return;

    int ylo4 = ylo >> 2;
    int yhi4 = (yhi + 3) >> 2;

    const uint2* f4 = (const uint2*)ws_f + (size_t)b * (Y4_ * W_ * C_);

    float acc[49];
#pragma unroll
    for (int q = 0; q < 49; ++q) acc[q] = 0.0f;
    int live = 0;

    for (int x = xs; x < xe; x += 4) {
        float cs[4][P_];
#pragma unroll
        for (int i = 0; i < 4; ++i)
#pragma unroll
            for (int py = 0; py < P_; ++py) cs[i][py] = 0.0f;

        const uint2* cp = f4 + ((size_t)(ylo4 * W_ + x)) * C_ + c;

        uint2 d0 = cp[0];
        uint2 d1 = cp[C_];
        uint2 d2 = cp[2 * C_];
        uint2 d3 = cp[3 * C_];
        for (int y4 = ylo4; y4 < yhi4; ++y4) {
            size_t nstep = (y4 + 1 < yhi4) ? (size_t)(W_ * C_) : 0;
            const uint2* cq = cp + nstep;
            uint2 e0 = cq[0];
            uint2 e1 = cq[C_];
            uint2 e2 = cq[2 * C_];
            uint2 e3 = cq[3 * C_];

            uint4 wa0 = *(const uint4*)&s_wy2[(2 * y4) * WROW_];
            uint4 wb0 = *(const uint4*)&s_wy2[(2 * y4) * WROW_ + 4];
            uint4 wa1 = *(const uint4*)&s_wy2[(2 * y4 + 1) * WROW_];
            uint4 wb1 = *(const uint4*)&s_wy2[(2 * y4 + 1) * WROW_ + 4];
            half2v w0[7], w1[7];
            w0[0] = __builtin_bit_cast(half2v, wa0.x);
            w0[1] = __builtin_bit_cast(half2v, wa0.y);
            w0[2] = __builtin_bit_cast(half2v, wa0.z);
            w0[3] = __builtin_bit_cast(half2v, wa0.w);
            w0[4] = __builtin_bit_cast(half2v, wb0.x);
            w0[5] = __builtin_bit_cast(half2v, wb0.y);
            w0[6] = __builtin_bit_cast(half2v, wb0.z);
            w1[0] = __builtin_bit_cast(half2v, wa1.x);
            w1[1] = __builtin_bit_cast(half2v, wa1.y);
            w1[2] = __builtin_bit_cast(half2v, wa1.z);
            w1[3] = __builtin_bit_cast(half2v, wa1.w);
            w1[4] = __builtin_bit_cast(half2v, wb1.x);
            w1[5] = __builtin_bit_cast(half2v, wb1.y);
            w1[6] = __builtin_bit_cast(half2v, wb1.z);
            half2v v0a = __builtin_bit_cast(half2v, d0.x);
            half2v v0b = __builtin_bit_cast(half2v, d0.y);
            half2v v1a = __builtin_bit_cast(half2v, d1.x);
            half2v v1b = __builtin_bit_cast(half2v, d1.y);
            half2v v2a = __builtin_bit_cast(half2v, d2.x);
            half2v v2b = __builtin_bit_cast(half2v, d2.y);
            half2v v3a = __builtin_bit_cast(half2v, d3.x);
            half2v v3b = __builtin_bit_cast(half2v, d3.y);
#pragma unroll
            for (int py = 0; py < P_; ++py) {
                cs[0][py] = FDOT2(w1[py], v0b, FDOT2(w0[py], v0a, cs[0][py]));
                cs[1][py] = FDOT2(w1[py], v1b, FDOT2(w0[py], v1a, cs[1][py]));
                cs[2][py] = FDOT2(w1[py], v2b, FDOT2(w0[py], v2a, cs[2][py]));
                cs[3][py] = FDOT2(w1[py], v3b, FDOT2(w0[py], v3a, cs[3][py]));
            }
            d0 = e0; d1 = e1; d2 = e2; d3 = e3;
            cp = cq;
        }

#pragma unroll
        for (int i = 0; i < 4; ++i) {
            if (x + i < xe) {
                float av[8];
                *(float4*)(&av[0]) = *(const float4*)&s_ax[x + i][0];
                *(float4*)(&av[4]) = *(const float4*)&s_ax[x + i][4];
#pragma unroll
                for (int px = 0; px < P_; ++px) {
                    float w = av[px];
                    if (w != 0.0f) {
                        live |= 1 << px;
#pragma unroll
                        for (int py = 0; py < P_; ++py)
                            acc[py * P_ + px] = fmaf(w, cs[i][py], acc[py * P_ + px]);
                    }
                }
            }
        }
    }

    float* os = outs + ((size_t)b * N_ + n) * (49 * C_) + c;
#pragma unroll
    for (int px = 0; px < P_; ++px) {
        if (live & (1 << px)) {
#pragma unroll
            for (int py = 0; py < P_; ++py)
                atomicAdd(os + (py * P_ + px) * C_, acc[py * P_ + px]);
        }
    }
}

__global__ __launch_bounds__(256) void k_final(const float* __restrict__ outs,
                                               float* __restrict__ out) {
    __shared__ float t[49 * 65];
    int bid = blockIdx.x;
    int cg  = bid & 3;
    int bn  = bid >> 2;
    int tid = (int)threadIdx.x;
    const float* src = outs + (size_t)bn * (49 * C_) + cg * 64;
    for (int e = tid; e < 49 * 64; e += 256) {
        int q = e >> 6, c = e & 63;
        t[q * 65 + c] = src[q * C_ + c];
    }
    __syncthreads();
    float* dst = out + (size_t)bn * (C_ * 49) + (size_t)cg * 64 * 49;
    for (int e = tid; e < 64 * 49; e += 256) {
        int c = e / 49, q = e - c * 49;
        dst[e] = t[q * 65 + c];
    }
}

// ---------------------------------------------------------------------------
extern "C" void kernel_launch(void* const* d_in, const int* in_sizes, int n_in,
                              void* d_out, int out_size, void* d_ws, size_t ws_size,
                              hipStream_t stream) {
    const float* fm    = (const float*)d_in[0];
    const float* boxes = (const float*)d_in[1];
    const float* gt    = (const float*)d_in[2];
    float* ws_f = (float*)d_ws;
    float* out  = (float*)d_out;

    if (ws_size >= WS_BYTES_P) {
        // ---- path P: atomic-free + exact y-sparsity (bitmask-guarded) ----
        float* part = ws_f + F_PART;
        k_prep<<<PREP_T, 256, 0, stream>>>(fm, ws_f);
        k_mainP<<<B_ * N_ * JP2_, 256, 0, stream>>>(ws_f, boxes, gt, part);
        k_reduce<<<B_ * N_ * 4, 256, 0, stream>>>(part, out);
    } else {
        // ---- fallback: R4-verbatim proven pipeline ----
        float* outs = ws_f + F_OUTS;
        k_prep<<<PREP_N, 256, 0, stream>>>(fm, ws_f);
        k_main<<<B_ * N_ * JPN_, 256, 0, stream>>>(ws_f, boxes, gt, outs);
        k_final<<<B_ * N_ * 4, 256, 0, stream>>>(outs, out);
    }
}

// Round 12
// 132.105 us; speedup vs baseline: 1.8966x; 1.0250x over previous
//
#include <hip/hip_runtime.h>

#define B_ 2
#define C_ 256
#define H_ 56
#define W_ 56
#define N_ 64
#define M_ 8
#define P_ 7
#define Y2_ (H_/2)               // 28 y-row pairs
#define Y4_ (H_/4)               // 14 y-row quads
#define SCTX_ 4                  // column chunks per ctx roi (box roi = whole)
#define JPN_ (1 + (M_)*SCTX_)    // 33 jobs per (b,n) -> 4224 blocks (fallback)
#define JP2_ (9*4)               // 36 px-pair jobs per (b,n) -> 4608 (path P)
#define WROW_ 8                  // padded weight-row stride (7 used + col7 = 0)

typedef _Float16 half2v __attribute__((ext_vector_type(2)));

#if __has_builtin(__builtin_amdgcn_fdot2)
#define FDOT2(a, b, c) __builtin_amdgcn_fdot2((a), (b), (c), false)
#else
static __device__ __forceinline__ float FDOT2(half2v a, half2v b, float c) {
    return fmaf((float)a.x, (float)b.x, fmaf((float)a.y, (float)b.y, c));
}
#endif

// ---- workspace layout (dword-element offsets) ----
#define F_FMT4 0
#define N_FMT4 (B_*Y4_*W_*C_*2)              // 802,816 dw  f16 y-QUAD-packed fmap
#define F_OUTS (F_FMT4 + N_FMT4)             // fallback: atomic staging
#define N_OUTS (B_*N_*49*C_)                 // 1,605,632 dw
#define WS_BYTES_F ((size_t)(F_OUTS + N_OUTS) * 4)       // 9.6 MB (proven)
// path P: plain-store partials.  part[bn][px][k 0..8][py][c]
#define F_PART (F_FMT4 + N_FMT4)
#define N_PART (B_*N_*7*9*7*C_)              // 14,450,688 dw = 57.8 MB
#define WS_BYTES_P ((size_t)(F_PART + N_PART) * 4)       // ~61.0 MB (ran R9-R11)

// prep kernel block ranges
#define PREPP_T (B_*Y4_*8*2)                 // 448: path-P transpose (32-ch groups)
#define PREP_T (B_*Y4_*4*2)                  // 224: fallback transpose
#define PREP_N (PREP_T + 784)                // fallback: + zero outS

// ---------------------------------------------------------------------------
// k_prepP (path P, R12): transpose with 8 channel-groups of 32 -> 448 blocks,
// 14 serial loads/thread instead of 28.  Same output layout as k_prep.
__global__ __launch_bounds__(256) void k_prepP(const float* __restrict__ fm,
                                               float* __restrict__ ws_f) {
    __shared__ float t[28 * 129 + 8];        // [x28][y4][c32], x-stride 129 pad
    int bid = blockIdx.x;
    int tid = (int)threadIdx.x;
    int xh = bid & 1;
    int cg = (bid >> 1) & 7;
    int y4 = (bid >> 4) % Y4_;
    int b  = (bid >> 4) / Y4_;
    int c0 = cg * 32, x0 = xh * 28;
    for (int e = tid; e < 32 * 4 * 28; e += 256) {   // 3584: 14 iters
        int c_l = e / 112, rem = e % 112;
        int y_l = rem / 28, x_l = rem % 28;
        t[x_l * 129 + y_l * 32 + c_l] =
            fm[(((size_t)b * C_ + c0 + c_l) * H_ + 4 * y4 + y_l) * W_ + x0 + x_l];
    }
    __syncthreads();
    uint2* dst = (uint2*)ws_f;
    for (int e = tid; e < 28 * 32; e += 256) {       // 896
        int x_l = e >> 5, c_l = e & 31;
        const float* p = &t[x_l * 129 + c_l];
        half2v lo, hi; uint2 o;
        lo.x = (_Float16)p[0];  lo.y = (_Float16)p[32];
        hi.x = (_Float16)p[64]; hi.y = (_Float16)p[96];
        o.x = __builtin_bit_cast(unsigned int, lo);
        o.y = __builtin_bit_cast(unsigned int, hi);
        dst[(((size_t)b * Y4_ + y4) * W_ + x0 + x_l) * (size_t)C_ + c0 + c_l] = o;
    }
}

// ---------------------------------------------------------------------------
// k_prep (fallback, R2-verified): transpose + zero outS.
__global__ __launch_bounds__(256) void k_prep(const float* __restrict__ fm,
                                              float* __restrict__ ws_f) {
    __shared__ float t[28 * 257 + 8];
    int bid = blockIdx.x;
    int tid = (int)threadIdx.x;

    if (bid < PREP_T) {
        int xh = bid & 1;
        int cg = (bid >> 1) & 3;
        int y4 = (bid >> 3) % Y4_;
        int b  = (bid >> 3) / Y4_;
        int c0 = cg * 64, x0 = xh * 28;
        for (int e = tid; e < 64 * 4 * 28; e += 256) {
            int c_l = e / 112, rem = e % 112;
            int y_l = rem / 28, x_l = rem % 28;
            t[x_l * 257 + y_l * 64 + c_l] =
                fm[(((size_t)b * C_ + c0 + c_l) * H_ + 4 * y4 + y_l) * W_ + x0 + x_l];
        }
        __syncthreads();
        uint2* dst = (uint2*)ws_f;
        for (int e = tid; e < 28 * 64; e += 256) {
            int x_l = e >> 6, c_l = e & 63;
            const float* p = &t[x_l * 257 + c_l];
            half2v lo, hi; uint2 o;
            lo.x = (_Float16)p[0];   lo.y = (_Float16)p[64];
            hi.x = (_Float16)p[128]; hi.y = (_Float16)p[192];
            o.x = __builtin_bit_cast(unsigned int, lo);
            o.y = __builtin_bit_cast(unsigned int, hi);
            dst[(((size_t)b * Y4_ + y4) * W_ + x0 + x_l) * (size_t)C_ + c0 + c_l] = o;
        }
        return;
    }

    {
        int tz = (bid - PREP_T) * 256 + tid;
        float4 z = {0.0f, 0.0f, 0.0f, 0.0f};
        float4* dst = (float4*)(ws_f + F_OUTS);
        dst[tz * 2]     = z;
        dst[tz * 2 + 1] = z;
    }
}

// ---------------------------------------------------------------------------
// Shared weight-gen (R0-proven serial column-private form).
static __device__ __forceinline__ void gen_weights(int k, int b, int n, int tid,
                                                   const float* __restrict__ boxes,
                                                   const float* __restrict__ gt,
                                                   float (*s_wyf)[WROW_],
                                                   unsigned int* s_wy2,
                                                   float (*s_ax)[WROW_],
                                                   float& bx1, float& by1,
                                                   float& rw, float& rh) {
    const float* bp = boxes + ((size_t)b * N_ + n) * 4;
    float bx2, by2;
    if (k == 0) {
        bx1 = bp[0]; by1 = bp[1]; bx2 = bp[2]; by2 = bp[3];
    } else {
        const float* gp = gt + ((size_t)b * M_ + (k - 1)) * 4;
        bx1 = fminf(bp[0], gp[0]); by1 = fminf(bp[1], gp[1]);
        bx2 = fmaxf(bp[2], gp[2]); by2 = fmaxf(bp[3], gp[3]);
    }
    rw = fmaxf(bx2 - bx1, 1.0f);
    rh = fmaxf(by2 - by1, 1.0f);

    for (int e = tid; e < H_ * WROW_; e += 256) ((float*)s_wyf)[e] = 0.0f;
    for (int e = tid; e < W_ * WROW_; e += 256) ((float*)s_ax)[e] = 0.0f;
    __syncthreads();

    if (tid < P_) {                          // y samples, column-private
        int p = tid;
        float bin = rh / 7.0f;
        float gf  = ceilf(bin);
        int   g   = (int)gf;
        float ivg = 1.0f / gf;
        float start = by1 + (float)p * bin;
        for (int ss = 0; ss < g; ++ss) {
            float coord = start + ((float)ss + 0.5f) * bin * ivg;
            if (coord < -1.0f || coord > (float)H_) continue;
            float cc = fmaxf(coord, 0.0f);
            int low = (int)floorf(cc);
            int high; float l;
            if (low >= H_ - 1) { low = H_ - 1; high = H_ - 1; l = 0.0f; }
            else               { high = low + 1; l = cc - (float)low; }
            s_wyf[low][p]  += (1.0f - l) * ivg;
            s_wyf[high][p] += l * ivg;
        }
    } else if (tid >= 64 && tid < 64 + P_) { // x samples, column-private
        int p = tid - 64;
        float bin = rw / 7.0f;
        float gf  = ceilf(bin);
        int   g   = (int)gf;
        float ivg = 1.0f / gf;
        float fs  = (k == 0) ? ivg : ivg * (1.0f / (float)M_);
        float start = bx1 + (float)p * bin;
        for (int ss = 0; ss < g; ++ss) {
            float coord = start + ((float)ss + 0.5f) * bin * ivg;
            if (coord < -1.0f || coord > (float)W_) continue;
            float cc = fmaxf(coord, 0.0f);
            int low = (int)floorf(cc);
            int high; float l;
            if (low >= W_ - 1) { low = W_ - 1; high = W_ - 1; l = 0.0f; }
            else               { high = low + 1; l = cc - (float)low; }
            s_ax[low][p]  += (1.0f - l) * fs;
            s_ax[high][p] += l * fs;
        }
    }
    __syncthreads();

    if (tid < Y2_ * WROW_) {                 // pack y fp32 pairs -> half2
        int q2 = tid >> 3, col = tid & 7;
        half2v h;
        if (col < P_) { h.x = (_Float16)s_wyf[2 * q2][col]; h.y = (_Float16)s_wyf[2 * q2 + 1][col]; }
        else          { h.x = (_Float16)0.0f; h.y = (_Float16)0.0f; }
        s_wy2[tid] = __builtin_bit_cast(unsigned int, h);
    }
    __syncthreads();
}

// one (py F) dot2 pair across the quad's 4 columns — ALL indices static
#define YQ3(F) \
    { cs[0][F] = FDOT2(w1[F], v0b, FDOT2(w0[F], v0a, cs[0][F]));   \
      cs[1][F] = FDOT2(w1[F], v1b, FDOT2(w0[F], v1a, cs[1][F]));   \
      cs[2][F] = FDOT2(w1[F], v2b, FDOT2(w0[F], v2a, cs[2][F]));   \
      cs[3][F] = FDOT2(w1[F], v3b, FDOT2(w0[F], v3a, cs[3][F])); }

// ---------------------------------------------------------------------------
// k_mainP (path P, R12): R11 body VERBATIM (proven 64.2us, VGPR 36, no
// spill) + XCD-PINNED job mapping.  fmt4 is 3.2MB/image; per-XCD L2 is 4MB.
// blockIdx round-robins across the 8 XCDs (m09), so with b = (bid&7)&1 each
// XCD only ever touches ONE image's fmt4 -> the working set L2-fits and the
// per-quad loads drop from mixed L3/HBM to L2 hits.  Bijective remap:
// xcd=bid&7, g=bid>>3, within-image job = g*4+(xcd>>1) in [0,2304).
// Perf-only heuristic — any (b,n,j) permutation is correct.
__global__ __launch_bounds__(256, 4) void k_mainP(const float* __restrict__ ws_f,
                                                  const float* __restrict__ boxes,
                                                  const float* __restrict__ gt,
                                                  float* __restrict__ part) {
    __shared__ float        s_wyf[H_][WROW_];
    __shared__ unsigned int s_wy2[Y2_ * WROW_];
    __shared__ float        s_ax[W_][WROW_];
    __shared__ int          s_lm[Y4_];       // live-py bitmask per quad

    int bid0 = (int)blockIdx.x;
    int xcd  = bid0 & 7;
    int g    = bid0 >> 3;                    // 0..575
    int b    = xcd & 1;                      // pin image to XCD parity
    int wj   = g * 4 + (xcd >> 1);           // 0..2303 within image
    int j    = wj % JP2_;                    // 0..35
    int n    = wj / JP2_;                    // 0..63
    int k    = j >> 2;                       // 0 = box, 1..8 = ctx union
    int s    = j & 3;
    int p0   = 2 * s;                        // px pair {p0,p0+1} (s==3: p0 only)
    int tid  = (int)threadIdx.x;
    int c    = tid;

    float bx1, by1, rw, rh;
    gen_weights(k, b, n, tid, boxes, gt, s_wyf, s_wy2, s_ax, bx1, by1, rw, rh);

    // ---- exact per-quad live-py bitmask (s_wyf stable after pack barrier) ----
    if (tid < Y4_) {
        int m = 0;
#pragma unroll
        for (int r = 0; r < 4; ++r)
#pragma unroll
            for (int p = 0; p < P_; ++p)
                if (s_wyf[4 * tid + r][p] != 0.0f) m |= 1 << p;
        s_lm[tid] = m;
    }
    __syncthreads();

    // ---- px-pair column support (R6-verified formulas) ----
    float binw = rw * (1.0f / 7.0f);
    float lo_f = bx1 + (float)p0 * binw;
    int   pe   = (p0 + 1 < P_) ? p0 + 2 : p0 + 1;
    float hi_f = bx1 + (float)pe * binw;
    int xs = min(max((int)floorf(fmaxf(lo_f, 0.0f)), 0), W_ - 1);
    int xe = min(max((int)floorf(fminf(hi_f, (float)W_)) + 1, 0), W_ - 1) + 1;

    int ylo = min(max((int)floorf(fmaxf(by1, 0.0f)), 0), H_ - 1);
    int yhi = min(max((int)floorf(by1 + rh) + 1, 0), H_ - 1) + 1;
    int ylo4 = ylo >> 2;
    int yhi4 = (yhi + 3) >> 2;

    const uint2* f4 = (const uint2*)ws_f + (size_t)b * (Y4_ * W_ * C_);

    float acc0[P_], acc1[P_];
#pragma unroll
    for (int q = 0; q < P_; ++q) { acc0[q] = 0.0f; acc1[q] = 0.0f; }

    if (xs < xe) {                           // empty support -> store zeros
        for (int x = xs; x < xe; x += 4) {
            float cs[4][P_];
#pragma unroll
            for (int i = 0; i < 4; ++i)
#pragma unroll
                for (int py = 0; py < P_; ++py) cs[i][py] = 0.0f;

            // x+1..x+3 over-reads stay inside d_ws; garbage never enters acc.
            const uint2* cp = f4 + ((size_t)(ylo4 * W_ + x)) * C_ + c;
            for (int y4 = ylo4; y4 < yhi4; ++y4) {
                int lm = s_lm[y4];
                if (lm == 0) { cp += W_ * C_; continue; }    // dead quad: skip
                uint2 d0 = cp[0];
                uint2 d1 = cp[C_];
                uint2 d2 = cp[2 * C_];
                uint2 d3 = cp[3 * C_];
                uint4 wa0 = *(const uint4*)&s_wy2[(2 * y4) * WROW_];
                uint4 wb0 = *(const uint4*)&s_wy2[(2 * y4) * WROW_ + 4];
                uint4 wa1 = *(const uint4*)&s_wy2[(2 * y4 + 1) * WROW_];
                uint4 wb1 = *(const uint4*)&s_wy2[(2 * y4 + 1) * WROW_ + 4];
                half2v w0[7], w1[7];
                w0[0] = __builtin_bit_cast(half2v, wa0.x);
                w0[1] = __builtin_bit_cast(half2v, wa0.y);
                w0[2] = __builtin_bit_cast(half2v, wa0.z);
                w0[3] = __builtin_bit_cast(half2v, wa0.w);
                w0[4] = __builtin_bit_cast(half2v, wb0.x);
                w0[5] = __builtin_bit_cast(half2v, wb0.y);
                w0[6] = __builtin_bit_cast(half2v, wb0.z);
                w1[0] = __builtin_bit_cast(half2v, wa1.x);
                w1[1] = __builtin_bit_cast(half2v, wa1.y);
                w1[2] = __builtin_bit_cast(half2v, wa1.z);
                w1[3] = __builtin_bit_cast(half2v, wa1.w);
                w1[4] = __builtin_bit_cast(half2v, wb1.x);
                w1[5] = __builtin_bit_cast(half2v, wb1.y);
                w1[6] = __builtin_bit_cast(half2v, wb1.z);
                half2v v0a = __builtin_bit_cast(half2v, d0.x);
                half2v v0b = __builtin_bit_cast(half2v, d0.y);
                half2v v1a = __builtin_bit_cast(half2v, d1.x);
                half2v v1b = __builtin_bit_cast(half2v, d1.y);
                half2v v2a = __builtin_bit_cast(half2v, d2.x);
                half2v v2b = __builtin_bit_cast(half2v, d2.y);
                half2v v3a = __builtin_bit_cast(half2v, d3.x);
                half2v v3b = __builtin_bit_cast(half2v, d3.y);

                if (lm & 0x01) YQ3(0)
                if (lm & 0x02) YQ3(1)
                if (lm & 0x04) YQ3(2)
                if (lm & 0x08) YQ3(3)
                if (lm & 0x10) YQ3(4)
                if (lm & 0x20) YQ3(5)
                if (lm & 0x40) YQ3(6)
                cp += W_ * C_;
            }

            // ---- x-stage: only the owned px pair ----
#pragma unroll
            for (int i = 0; i < 4; ++i) {
                if (x + i < xe) {                     // wave-uniform
                    float2 axv = *(const float2*)&s_ax[x + i][p0];
#pragma unroll
                    for (int py = 0; py < P_; ++py) {
                        acc0[py] = fmaf(axv.x, cs[i][py], acc0[py]);
                        acc1[py] = fmaf(axv.y, cs[i][py], acc1[py]);
                    }
                }
            }
        }
    }

    // ---- epilogue: PLAIN coalesced stores to private slots ----
    size_t bn = (size_t)b * N_ + n;
    float* pp = part + (((bn * 7 + p0) * 9 + k) * 7) * 256 + c;
#pragma unroll
    for (int py = 0; py < P_; ++py) pp[py * 256] = acc0[py];
    if (p0 + 1 < P_) {
        float* pq = part + (((bn * 7 + p0 + 1) * 9 + k) * 7) * 256 + c;
#pragma unroll
        for (int py = 0; py < P_; ++py) pq[py * 256] = acc1[py];
    }
}

// ---------------------------------------------------------------------------
// k_reduce (path P, R12): float4-vectorized — 27x16B loads/thread instead of
// 110x4B.  Same math/layout as the R9-proven version.
__global__ __launch_bounds__(256) void k_reduce(const float* __restrict__ part,
                                                float* __restrict__ out) {
    __shared__ float t[49 * 65];
    int bid = blockIdx.x;                    // bn*4 + cg
    int cg  = bid & 3;
    int bn  = bid >> 2;
    int tid = (int)threadIdx.x;
    const float4* pb4 = (const float4*)(part + (size_t)bn * (7 * 9 * 7 * 256) + cg * 64);
    for (int e = tid; e < 49 * 16; e += 256) {       // 784 float4 sums
        int q = e >> 4, c4 = e & 15;
        int py = q / 7, px = q - py * 7;
        const float4* p0 = pb4 + (size_t)(px * 63 + py) * 64 + c4;
        float4 sum = {0.0f, 0.0f, 0.0f, 0.0f};
#pragma unroll
        for (int k = 0; k < 9; ++k) {
            float4 v = p0[(size_t)k * 448];
            sum.x += v.x; sum.y += v.y; sum.z += v.z; sum.w += v.w;
        }
        float* tq = &t[q * 65 + c4 * 4];
        tq[0] = sum.x; tq[1] = sum.y; tq[2] = sum.z; tq[3] = sum.w;
    }
    __syncthreads();
    float* dst = out + (size_t)bn * (C_ * 49) + (size_t)cg * 64 * 49;
    for (int e = tid; e < 64 * 49; e += 256) {
        int cl = e / 49, q = e - cl * 49;
        dst[e] = t[q * 65 + cl];
    }
}

// ---------------------------------------------------------------------------
// FALLBACK PATH (ws too small): R4-verbatim k_main + k_final (proven 149.4).
__global__ __launch_bounds__(256, 4) void k_main(const float* __restrict__ ws_f,
                                                 const float* __restrict__ boxes,
                                                 const float* __restrict__ gt,
                                                 float* __restrict__ outs) {
    __shared__ float        s_wyf[H_][WROW_];
    __shared__ unsigned int s_wy2[Y2_ * WROW_];
    __shared__ float        s_ax[W_][WROW_];

    int bid = blockIdx.x;
    int j   = bid % JPN_;
    int n   = (bid / JPN_) & (N_ - 1);
    int b   = bid / (JPN_ * N_);
    int k, s;
    if (j == 0) { k = 0; s = 0; }
    else        { k = 1 + ((j - 1) >> 2); s = (j - 1) & 3; }
    int tid = (int)threadIdx.x;
    int c   = tid;

    float bx1, by1, rw, rh;
    gen_weights(k, b, n, tid, boxes, gt, s_wyf, s_wy2, s_ax, bx1, by1, rw, rh);

    int xlo = min(max((int)floorf(fmaxf(bx1, 0.0f)), 0), W_ - 1);
    int xhi = min(max((int)floorf(bx1 + rw) + 1, 0), W_ - 1) + 1;
    int ylo = min(max((int)floorf(fmaxf(by1, 0.0f)), 0), H_ - 1);
    int yhi = min(max((int)floorf(by1 + rh) + 1, 0), H_ - 1) + 1;
    int xs, xe;
    if (k == 0) { xs = xlo; xe = xhi; }
    else {
        int cw = (xhi - xlo + SCTX_ - 1) >> 2;
        xs = xlo + s * cw;
        xe = min(xs + cw, xhi);
    }
    if (xs >= xe) return;

    int ylo4 = ylo >> 2;
    int yhi4 = (yhi + 3) >> 2;

    const uint2* f4 = (const uint2*)ws_f + (size_t)b * (Y4_ * W_ * C_);

    float acc[49];
#pragma unroll
    for (int q = 0; q < 49; ++q) acc[q] = 0.0f;
    int live = 0;

    for (int x = xs; x < xe; x += 4) {
        float cs[4][P_];
#pragma unroll
        for (int i = 0; i < 4; ++i)
#pragma unroll
            for (int py = 0; py < P_; ++py) cs[i][py] = 0.0f;

        const uint2* cp = f4 + ((size_t)(ylo4 * W_ + x)) * C_ + c;

        uint2 d0 = cp[0];
        uint2 d1 = cp[C_];
        uint2 d2 = cp[2 * C_];
        uint2 d3 = cp[3 * C_];
        for (int y4 = ylo4; y4 < yhi4; ++y4) {
            size_t nstep = (y4 + 1 < yhi4) ? (size_t)(W_ * C_) : 0;
            const uint2* cq = cp + nstep;
            uint2 e0 = cq[0];
            uint2 e1 = cq[C_];
            uint2 e2 = cq[2 * C_];
            uint2 e3 = cq[3 * C_];

            uint4 wa0 = *(const uint4*)&s_wy2[(2 * y4) * WROW_];
            uint4 wb0 = *(const uint4*)&s_wy2[(2 * y4) * WROW_ + 4];
            uint4 wa1 = *(const uint4*)&s_wy2[(2 * y4 + 1) * WROW_];
            uint4 wb1 = *(const uint4*)&s_wy2[(2 * y4 + 1) * WROW_ + 4];
            half2v w0[7], w1[7];
            w0[0] = __builtin_bit_cast(half2v, wa0.x);
            w0[1] = __builtin_bit_cast(half2v, wa0.y);
            w0[2] = __builtin_bit_cast(half2v, wa0.z);
            w0[3] = __builtin_bit_cast(half2v, wa0.w);
            w0[4] = __builtin_bit_cast(half2v, wb0.x);
            w0[5] = __builtin_bit_cast(half2v, wb0.y);
            w0[6] = __builtin_bit_cast(half2v, wb0.z);
            w1[0] = __builtin_bit_cast(half2v, wa1.x);
            w1[1] = __builtin_bit_cast(half2v, wa1.y);
            w1[2] = __builtin_bit_cast(half2v, wa1.z);
            w1[3] = __builtin_bit_cast(half2v, wa1.w);
            w1[4] = __builtin_bit_cast(half2v, wb1.x);
            w1[5] = __builtin_bit_cast(half2v, wb1.y);
            w1[6] = __builtin_bit_cast(half2v, wb1.z);
            half2v v0a = __builtin_bit_cast(half2v, d0.x);
            half2v v0b = __builtin_bit_cast(half2v, d0.y);
            half2v v1a = __builtin_bit_cast(half2v, d1.x);
            half2v v1b = __builtin_bit_cast(half2v, d1.y);
            half2v v2a = __builtin_bit_cast(half2v, d2.x);
            half2v v2b = __builtin_bit_cast(half2v, d2.y);
            half2v v3a = __builtin_bit_cast(half2v, d3.x);
            half2v v3b = __builtin_bit_cast(half2v, d3.y);
#pragma unroll
            for (int py = 0; py < P_; ++py) {
                cs[0][py] = FDOT2(w1[py], v0b, FDOT2(w0[py], v0a, cs[0][py]));
                cs[1][py] = FDOT2(w1[py], v1b, FDOT2(w0[py], v1a, cs[1][py]));
                cs[2][py] = FDOT2(w1[py], v2b, FDOT2(w0[py], v2a, cs[2][py]));
                cs[3][py] = FDOT2(w1[py], v3b, FDOT2(w0[py], v3a, cs[3][py]));
            }
            d0 = e0; d1 = e1; d2 = e2; d3 = e3;
            cp = cq;
        }

#pragma unroll
        for (int i = 0; i < 4; ++i) {
            if (x + i < xe) {
                float av[8];
                *(float4*)(&av[0]) = *(const float4*)&s_ax[x + i][0];
                *(float4*)(&av[4]) = *(const float4*)&s_ax[x + i][4];
#pragma unroll
                for (int px = 0; px < P_; ++px) {
                    float w = av[px];
                    if (w != 0.0f) {
                        live |= 1 << px;
#pragma unroll
                        for (int py = 0; py < P_; ++py)
                            acc[py * P_ + px] = fmaf(w, cs[i][py], acc[py * P_ + px]);
                    }
                }
            }
        }
    }

    float* os = outs + ((size_t)b * N_ + n) * (49 * C_) + c;
#pragma unroll
    for (int px = 0; px < P_; ++px) {
        if (live & (1 << px)) {
#pragma unroll
            for (int py = 0; py < P_; ++py)
                atomicAdd(os + (py * P_ + px) * C_, acc[py * P_ + px]);
        }
    }
}

__global__ __launch_bounds__(256) void k_final(const float* __restrict__ outs,
                                               float* __restrict__ out) {
    __shared__ float t[49 * 65];
    int bid = blockIdx.x;
    int cg  = bid & 3;
    int bn  = bid >> 2;
    int tid = (int)threadIdx.x;
    const float* src = outs + (size_t)bn * (49 * C_) + cg * 64;
    for (int e = tid; e < 49 * 64; e += 256) {
        int q = e >> 6, c = e & 63;
        t[q * 65 + c] = src[q * C_ + c];
    }
    __syncthreads();
    float* dst = out + (size_t)bn * (C_ * 49) + (size_t)cg * 64 * 49;
    for (int e = tid; e < 64 * 49; e += 256) {
        int c = e / 49, q = e - c * 49;
        dst[e] = t[q * 65 + c];
    }
}

// ---------------------------------------------------------------------------
extern "C" void kernel_launch(void* const* d_in, const int* in_sizes, int n_in,
                              void* d_out, int out_size, void* d_ws, size_t ws_size,
                              hipStream_t stream) {
    const float* fm    = (const float*)d_in[0];
    const float* boxes = (const float*)d_in[1];
    const float* gt    = (const float*)d_in[2];
    float* ws_f = (float*)d_ws;
    float* out  = (float*)d_out;

    if (ws_size >= WS_BYTES_P) {
        // ---- path P: atomic-free + y-sparsity + XCD-pinned L2 locality ----
        float* part = ws_f + F_PART;
        k_prepP<<<PREPP_T, 256, 0, stream>>>(fm, ws_f);
        k_mainP<<<B_ * N_ * JP2_, 256, 0, stream>>>(ws_f, boxes, gt, part);
        k_reduce<<<B_ * N_ * 4, 256, 0, stream>>>(part, out);
    } else {
        // ---- fallback: R4-verbatim proven pipeline ----
        float* outs = ws_f + F_OUTS;
        k_prep<<<PREP_N, 256, 0, stream>>>(fm, ws_f);
        k_main<<<B_ * N_ * JPN_, 256, 0, stream>>>(ws_f, boxes, gt, outs);
        k_final<<<B_ * N_ * 4, 256, 0, stream>>>(outs, out);
    }
}